// Round 4
// baseline (37.161 us; speedup 1.0000x reference)
//
#include <hip/hip_runtime.h>

typedef __attribute__((ext_vector_type(8))) short bf16x8;   // 8 bf16 (4 VGPRs)
typedef __attribute__((ext_vector_type(4))) float f32x4;

#define BM 128
#define BN 128

__device__ inline unsigned short f2bf(float f) {
  unsigned int u = __builtin_bit_cast(unsigned int, f);
  u += 0x7fffu + ((u >> 16) & 1u);     // round-to-nearest-even
  return (unsigned short)(u >> 16);
}

__device__ inline void gload16(const void* g, void* l) {
  __builtin_amdgcn_global_load_lds(
      (const __attribute__((address_space(1))) void*)g,
      (__attribute__((address_space(3))) void*)l, 16, 0, 0);
}

// C is tiny (512x256): convert once -> bf16, pre-XOR-swizzled within each
// 128B block (byte ^= (row&7)<<4), + exact fp32 csq. One wave per row.
__global__ void prep_c(const float* __restrict__ C, unsigned short* __restrict__ Cbf,
                       float* __restrict__ csq, int K) {
  const int w = threadIdx.x >> 6, lane = threadIdx.x & 63;
  const int row = blockIdx.x * 4 + w;
  if (row >= K) return;
  const float4 v = *reinterpret_cast<const float4*>(&C[(size_t)row * 256 + lane * 4]);
  ushort4 b;
  b.x = f2bf(v.x); b.y = f2bf(v.y); b.z = f2bf(v.z); b.w = f2bf(v.w);
  const int boff = (lane * 8) ^ ((row & 7) << 4);
  *reinterpret_cast<ushort4*>((char*)Cbf + (size_t)row * 512 + boff) = b;
  float sq = v.x * v.x + v.y * v.y + v.z * v.z + v.w * v.w;
#pragma unroll
  for (int o = 32; o; o >>= 1) sq += __shfl_xor(sq, o);
  if (lane == 0) csq[row] = sq;
}

// Fused: out[m][n] = ||F_m||^2 + ||C_n||^2 - 2*F_m.C_n
// A staged as RAW FP32 via global_load_lds (swizzled source, linear dest);
// fp32->bf16 conversion + row-norm accumulation happen in the compute phase
// from the A-fragments (VALU is idle there). B staged from pre-swizzled bf16.
// 128x128 tile, BK=64 (4 K-iters), 4 waves (2x2), 3 blocks/CU.
__global__ __launch_bounds__(256, 3) void dist_fused(
    const float* __restrict__ F, const unsigned short* __restrict__ Cbf,
    const float* __restrict__ csq, float* __restrict__ out, int M, int N) {
  __shared__ __align__(16) char Asb[BM * 256];   // fp32 tile: 128 rows x 256B (64 f32), swizzled
  __shared__ __align__(16) char Bsb[BN * 128];   // bf16 tile: 128 rows x 128B (64 bf16), swizzled
  __shared__ float fsq_s[BM];

  const int t = threadIdx.x;
  const int w = t >> 6, lane = t & 63;
  const int wr = w >> 1, wc = w & 1;          // wave -> 64x64 quadrant
  const int rl = lane & 15, kh = lane >> 4;   // fragment lane decomposition
  const int amask = (rl & 7) << 4;            // read-side XOR

  // Bijective XCD swizzle (1024 blocks, %8==0); n-tile fastest so the 4
  // blocks sharing an F m-panel run consecutively on the same XCD.
  const int nwg = gridDim.x;
  const int cpx = nwg >> 3;
  const int work = (blockIdx.x & 7) * cpx + (blockIdx.x >> 3);
  const int ntiles = N / BN;                  // 4
  const int n0 = (work % ntiles) * BN;
  const int m0 = (work / ntiles) * BM;

  // csq prefetch (L2-hot, hides under staging)
  float cs[4];
#pragma unroll
  for (int ni = 0; ni < 4; ni++) cs[ni] = csq[n0 + wc * 64 + ni * 16 + rl];

  f32x4 acc[4][4];
#pragma unroll
  for (int i = 0; i < 4; i++)
#pragma unroll
    for (int j = 0; j < 4; j++) acc[i][j] = (f32x4){0.f, 0.f, 0.f, 0.f};
  float rsq[4] = {0.f, 0.f, 0.f, 0.f};

  // staging decompositions (thread-constant)
  const int a_r16 = t >> 4;                                   // 0..15
  const int a_cb = ((t & 15) * 16) ^ ((a_r16 & 7) << 4);      // swizzled src col in 256B K-tile
  const int b_r32 = t >> 3;                                   // 0..31
  const int b_cb = (t & 7) * 16;

  for (int kt = 0; kt < 4; ++kt) {
    // A: 32KB = 8 rounds of 4KB. dest linear; source swizzled (rule #21).
#pragma unroll
    for (int j = 0; j < 8; ++j)
      gload16((const char*)F + (size_t)(m0 + j * 16 + a_r16) * 1024 + kt * 256 + a_cb,
              Asb + j * 4096 + w * 1024);
    // B: 16KB = 4 rounds. source already swizzled in memory.
#pragma unroll
    for (int j = 0; j < 4; ++j)
      gload16((const char*)Cbf + (size_t)(n0 + j * 32 + b_r32) * 512 + kt * 128 + b_cb,
              Bsb + j * 4096 + w * 1024);
    __syncthreads();   // compiler drains vmcnt before barrier

#pragma unroll
    for (int kk = 0; kk < 2; ++kk) {
      bf16x8 bfr[4];
#pragma unroll
      for (int ni = 0; ni < 4; ni++)
        bfr[ni] = *reinterpret_cast<const bf16x8*>(
            Bsb + (wc * 64 + ni * 16 + rl) * 128 + ((kk * 64 + kh * 16) ^ amask));
#pragma unroll
      for (int mi = 0; mi < 4; mi++) {
        const char* arow = Asb + (wr * 64 + mi * 16 + rl) * 256;
        const int c0 = (kk * 128 + kh * 32) ^ amask;
        const int c1 = (kk * 128 + kh * 32 + 16) ^ amask;
        const f32x4 a0 = *reinterpret_cast<const f32x4*>(arow + c0);
        const f32x4 a1 = *reinterpret_cast<const f32x4*>(arow + c1);
        rsq[mi] += a0[0] * a0[0] + a0[1] * a0[1] + a0[2] * a0[2] + a0[3] * a0[3] +
                   a1[0] * a1[0] + a1[1] * a1[1] + a1[2] * a1[2] + a1[3] * a1[3];
        bf16x8 af;
        af[0] = (short)f2bf(a0[0]); af[1] = (short)f2bf(a0[1]);
        af[2] = (short)f2bf(a0[2]); af[3] = (short)f2bf(a0[3]);
        af[4] = (short)f2bf(a1[0]); af[5] = (short)f2bf(a1[1]);
        af[6] = (short)f2bf(a1[2]); af[7] = (short)f2bf(a1[3]);
#pragma unroll
        for (int ni = 0; ni < 4; ni++)
          acc[mi][ni] = __builtin_amdgcn_mfma_f32_16x16x32_bf16(
              af, bfr[ni], acc[mi][ni], 0, 0, 0);
      }
    }
    __syncthreads();
  }

  // Row norms: lane holds the kh-slice partial for rows wr*64+mi*16+rl.
  // Reduce across kh groups (lanes rl, rl+16, rl+32, rl+48), publish once.
#pragma unroll
  for (int mi = 0; mi < 4; mi++) {
    float v = rsq[mi];
    v += __shfl_xor(v, 16);
    v += __shfl_xor(v, 32);
    if (wc == 0 && lane < 16) fsq_s[wr * 64 + mi * 16 + lane] = v;
  }
  __syncthreads();

  // Epilogue: C/D layout col = lane&15, row = (lane>>4)*4 + reg  [m89/m91]
#pragma unroll
  for (int mi = 0; mi < 4; mi++) {
    const int rloc = wr * 64 + mi * 16 + kh * 4;
    float fr[4];
#pragma unroll
    for (int r = 0; r < 4; r++) fr[r] = fsq_s[rloc + r];
#pragma unroll
    for (int ni = 0; ni < 4; ni++) {
      const int cloc = wc * 64 + ni * 16 + rl;
#pragma unroll
      for (int r = 0; r < 4; r++)
        out[(size_t)(m0 + rloc + r) * N + n0 + cloc] =
            fr[r] + cs[ni] - 2.0f * acc[mi][ni][r];
    }
  }
}

extern "C" void kernel_launch(void* const* d_in, const int* in_sizes, int n_in,
                              void* d_out, int out_size, void* d_ws, size_t ws_size,
                              hipStream_t stream) {
  const float* F = (const float*)d_in[0];   // (16, 2048, 256) fp32
  const float* C = (const float*)d_in[1];   // (1, 512, 256) fp32
  float* out = (float*)d_out;               // (16, 2048, 512) fp32
  const int D = 256;
  const int M = in_sizes[0] / D;            // 32768
  const int N = in_sizes[1] / D;            // 512

  unsigned short* Cbf = (unsigned short*)d_ws;    // N*256 bf16 (swizzled)
  float* csq = (float*)(Cbf + (size_t)N * D);     // N fp32

  hipLaunchKernelGGL(prep_c, dim3(N / 4), dim3(256), 0, stream, C, Cbf, csq, N);
  const int nwg = (M / BM) * (N / BN);            // 1024, divisible by 8
  hipLaunchKernelGGL(dist_fused, dim3(nwg), dim3(256), 0, stream,
                     F, Cbf, csq, out, M, N);
}

// Round 6
// 32.392 us; speedup vs baseline: 1.1472x; 1.1472x over previous
//
#include <hip/hip_runtime.h>

typedef __attribute__((ext_vector_type(8))) short bf16x8;   // 8 bf16 (4 VGPRs)
typedef __attribute__((ext_vector_type(4))) float f32x4;

#define D_DIM 256   // feature dim (bf16 row = 512 B)
#define BM 128
#define BN 128
#define BK 64       // K-step in elements (128 B per row-chunk)

__device__ inline unsigned short f2bf(float f) {
  unsigned int u = __builtin_bit_cast(unsigned int, f);
  u += 0x7fffu + ((u >> 16) & 1u);     // round-to-nearest-even
  return (unsigned short)(u >> 16);
}

__device__ inline void gload16(const void* g, void* l) {
  __builtin_amdgcn_global_load_lds(
      (const __attribute__((address_space(1))) void*)g,
      (__attribute__((address_space(3))) void*)l, 16, 0, 0);
}

// One wave per row. Writes bf16 copy PRE-XOR-SWIZZLED (byte ^= (row&7)<<4,
// a permutation within each 128B sub-block of the 512B row) + exact fp32
// sum-of-squares. Rows [0,M) from F -> Abf/fsq; rows [M,M+K) from C -> Cbf/csq.
__global__ void prep_rows(const float* __restrict__ F, const float* __restrict__ C,
                          unsigned short* __restrict__ Abf, unsigned short* __restrict__ Cbf,
                          float* __restrict__ fsq, float* __restrict__ csq, int M) {
  const int w = threadIdx.x >> 6, lane = threadIdx.x & 63;
  int row = blockIdx.x * 4 + w;
  const float* src;
  unsigned short* dst;
  float* rsq;
  if (row < M) {
    src = F; dst = Abf; rsq = fsq;
  } else {
    row -= M;
    src = C; dst = Cbf; rsq = csq;
  }
  const float4 v = *reinterpret_cast<const float4*>(&src[(size_t)row * D_DIM + lane * 4]);
  ushort4 b;
  b.x = f2bf(v.x); b.y = f2bf(v.y); b.z = f2bf(v.z); b.w = f2bf(v.w);
  const int boff = (lane * 8) ^ ((row & 7) << 4);   // swizzled byte offset in 512B row
  *reinterpret_cast<ushort4*>((char*)dst + (size_t)row * 512 + boff) = b;
  float sq = v.x * v.x + v.y * v.y + v.z * v.z + v.w * v.w;
#pragma unroll
  for (int o = 32; o; o >>= 1) sq += __shfl_xor(sq, o);
  if (lane == 0) rsq[row] = sq;
}

// out[m][n] = fsq[m] + csq[n] - 2 * sum_d A[m][d]*B[n][d]
// A: M x 256 bf16 (pre-swizzled rows), B: N x 256 bf16 (pre-swizzled rows).
// Staging is LINEAR source columns -> LDS holds physical (swizzled) data ->
// read-side XOR unswizzles (rule #21: swizzle applied once per side).
// 128x128 tile, BK=64 (4 K-iters), 4 waves (2x2), double-buffered LDS with
// counted vmcnt(8): next tile's global_load_lds stay in flight across the
// barrier. 2 blocks/CU.
__global__ __launch_bounds__(256, 2) void dist_gemm(
    const unsigned short* __restrict__ A, const unsigned short* __restrict__ B,
    const float* __restrict__ fsq, const float* __restrict__ csq,
    float* __restrict__ out, int M, int N) {
  __shared__ __align__(16) char As[2][BM * 128];   // 2 x 16 KB
  __shared__ __align__(16) char Bs[2][BN * 128];   // 2 x 16 KB

  const int t = threadIdx.x;
  const int w = t >> 6, lane = t & 63;
  const int wr = w >> 1, wc = w & 1;          // wave -> 64x64 quadrant
  const int rl = lane & 15, kh = lane >> 4;   // fragment lane decomposition
  const int amask = (rl & 7) << 4;            // read-side XOR (row key: row&7 == rl&7)

  // Bijective XCD swizzle (1024 blocks, %8==0); n-tile fastest so the 4
  // blocks sharing an A m-panel run consecutively on the same XCD.
  const int nwg = gridDim.x;
  const int cpx = nwg >> 3;
  const int work = (blockIdx.x & 7) * cpx + (blockIdx.x >> 3);
  const int ntiles = N / BN;                  // 4
  const int n0 = (work % ntiles) * BN;
  const int m0 = (work / ntiles) * BM;

  // staging decomposition (thread-constant): 4 rounds x 32 rows, 16B/lane.
  // Source column LINEAR — memory is already swizzled; LDS dest linear.
  const int s_row = t >> 3;                   // 0..31
  const int s_cb = (t & 7) * 16;              // linear col byte in 128B chunk
  const char* Asrc = (const char*)A + (size_t)(m0 + s_row) * 512 + s_cb;
  const char* Bsrc = (const char*)B + (size_t)(n0 + s_row) * 512 + s_cb;
  // j-round advance: 32 rows * 512 B = 16384 B; K-step advance: 128 B.

  // prologue: stage kt=0 into buffer 0 (8 loads in flight)
#pragma unroll
  for (int j = 0; j < 4; ++j)
    gload16(Asrc + j * 16384, (char*)As[0] + j * 4096 + w * 1024);
#pragma unroll
  for (int j = 0; j < 4; ++j)
    gload16(Bsrc + j * 16384, (char*)Bs[0] + j * 4096 + w * 1024);

  // norm-term prefetch (L2-hot; completes before the first counted waitcnt)
  float fr[4][4];
#pragma unroll
  for (int mi = 0; mi < 4; mi++)
#pragma unroll
    for (int r = 0; r < 4; r++)
      fr[mi][r] = fsq[m0 + wr * 64 + mi * 16 + kh * 4 + r];
  float cs[4];
#pragma unroll
  for (int ni = 0; ni < 4; ni++)
    cs[ni] = csq[n0 + wc * 64 + ni * 16 + rl];

  f32x4 acc[4][4];
#pragma unroll
  for (int i = 0; i < 4; i++)
#pragma unroll
    for (int j = 0; j < 4; j++) acc[i][j] = (f32x4){0.f, 0.f, 0.f, 0.f};

#pragma unroll
  for (int kt = 0; kt < 4; ++kt) {
    const int cur = kt & 1;
    if (kt < 3) {
      const int nxt = cur ^ 1;
      // issue next K-tile's loads; they stay in flight across the barrier
#pragma unroll
      for (int j = 0; j < 4; ++j)
        gload16(Asrc + (kt + 1) * 128 + j * 16384, (char*)As[nxt] + j * 4096 + w * 1024);
#pragma unroll
      for (int j = 0; j < 4; ++j)
        gload16(Bsrc + (kt + 1) * 128 + j * 16384, (char*)Bs[nxt] + j * 4096 + w * 1024);
      asm volatile("s_waitcnt vmcnt(8)" ::: "memory");   // current tile landed; next 8 in flight
    } else {
      asm volatile("s_waitcnt vmcnt(0)" ::: "memory");   // last tile: drain
    }
    __builtin_amdgcn_s_barrier();
    asm volatile("" ::: "memory");   // pin ds_reads after the barrier (compiler fence)

#pragma unroll
    for (int kk = 0; kk < 2; ++kk) {
      const int soff = (kk * 64 + kh * 16) ^ amask;
      bf16x8 af[4], bfr[4];
#pragma unroll
      for (int mi = 0; mi < 4; mi++)
        af[mi] = *reinterpret_cast<const bf16x8*>(
            (const char*)As[cur] + (wr * 64 + mi * 16 + rl) * 128 + soff);
#pragma unroll
      for (int ni = 0; ni < 4; ni++)
        bfr[ni] = *reinterpret_cast<const bf16x8*>(
            (const char*)Bs[cur] + (wc * 64 + ni * 16 + rl) * 128 + soff);
#pragma unroll
      for (int mi = 0; mi < 4; mi++)
#pragma unroll
        for (int ni = 0; ni < 4; ni++)
          acc[mi][ni] = __builtin_amdgcn_mfma_f32_16x16x32_bf16(
              af[mi], bfr[ni], acc[mi][ni], 0, 0, 0);
    }
    __builtin_amdgcn_s_barrier();    // all waves done reading buf[cur] before restage
    asm volatile("" ::: "memory");   // pin next iteration's staging after the barrier
  }

  // Epilogue: C/D layout col = lane&15, row = (lane>>4)*4 + reg  [m89/m91]
#pragma unroll
  for (int mi = 0; mi < 4; mi++) {
    const int rloc = wr * 64 + mi * 16 + kh * 4;
#pragma unroll
    for (int ni = 0; ni < 4; ni++) {
      const int cloc = wc * 64 + ni * 16 + rl;
#pragma unroll
      for (int r = 0; r < 4; r++)
        out[(size_t)(m0 + rloc + r) * N + n0 + cloc] =
            fr[mi][r] + cs[ni] - 2.0f * acc[mi][ni][r];
    }
  }
}

extern "C" void kernel_launch(void* const* d_in, const int* in_sizes, int n_in,
                              void* d_out, int out_size, void* d_ws, size_t ws_size,
                              hipStream_t stream) {
  const float* F = (const float*)d_in[0];   // (16, 2048, 256) fp32
  const float* C = (const float*)d_in[1];   // (1, 512, 256) fp32
  float* out = (float*)d_out;               // (16, 2048, 512) fp32
  const int M = in_sizes[0] / D_DIM;        // 32768
  const int N = in_sizes[1] / D_DIM;        // 512

  unsigned short* Abf = (unsigned short*)d_ws;            // M*256 bf16 (swizzled)
  unsigned short* Cbf = Abf + (size_t)M * D_DIM;          // N*256 bf16 (swizzled)
  float* fsq = (float*)(Cbf + (size_t)N * D_DIM);         // M fp32
  float* csq = fsq + M;                                   // N fp32

  hipLaunchKernelGGL(prep_rows, dim3((M + N) / 4), dim3(256), 0, stream,
                     F, C, Abf, Cbf, fsq, csq, M);
  const int nwg = (M / BM) * (N / BN);      // 1024, divisible by 8
  hipLaunchKernelGGL(dist_gemm, dim3(nwg), dim3(256), 0, stream,
                     Abf, Cbf, fsq, csq, out, M, N);
}